// Round 7
// baseline (166.226 us; speedup 1.0000x reference)
//
#include <hip/hip_runtime.h>

// NonImagingRod: per-ray damped-Newton (LM) root find on f(t) = A t^2 + B t + C.
// Round-7: EXACT round-6 skeleton; ONLY change = v_rcp_f32 eliminated from the
// inner loop (magic-initial-guess + 3 Newton steps, all full-rate VALU).
// Rationale: R1 and R6 have IDENTICAL 66 us duration despite 1.6x different
// VALU op counts (VALUBusy 52% vs 32%) — the invariant is the per-iteration
// v_rcp_f32 stream; the shared transcendental pipe (~20 CU-cyc/wave-rcp) is
// the suspected pin. Newton-from-magic is unconditionally stable (fresh guess
// each iteration, ~10% -> 1e-8 rel err after 3 steps == rcp accuracy).
//
// Codegen notes (hard-won):
//  - 8 rays/thread (any source form): allocator pins VGPR at 32-36 and spills
//    the live set (VALUBusy 16%, 2x slower). Stay at 4 rays/thread.
//  - Clamp(+-1000) dropped: |A|<=c=0.05 (unit V) -> provably inactive
//    (absmax 0.0, rounds 2-6).

#define LM_ITERS 31
constexpr float DAMPING = 0.5f;

__global__ __launch_bounds__(256) void rod_kernel(
    const float* __restrict__ P, const float* __restrict__ V,
    const float* __restrict__ Rm, const float* __restrict__ Tv,
    const float* __restrict__ c_ptr, double* __restrict__ ws, int n)
{
    const float c  = c_ptr[0];
    const float r00 = Rm[0], r01 = Rm[1], r02 = Rm[2];
    const float r10 = Rm[3], r11 = Rm[4], r12 = Rm[5];
    const float r20 = Rm[6], r21 = Rm[7], r22 = Rm[8];
    const float t0 = Tv[0], t1 = Tv[1], t2 = Tv[2];

    const int tid  = blockIdx.x * blockDim.x + threadIdx.x;
    const int base = tid * 4;

    double acc = 0.0;
    if (base < n) {
        // 4 rays per thread: 3 float4 loads from each of P and V (n % 4 == 0).
        const float4* P4 = (const float4*)P;
        const float4* V4 = (const float4*)V;
        float4 pa = P4[tid * 3 + 0], pb = P4[tid * 3 + 1], pcv = P4[tid * 3 + 2];
        float4 va = V4[tid * 3 + 0], vb = V4[tid * 3 + 1], vcv = V4[tid * 3 + 2];

        const float px[4] = {pa.x, pa.w, pb.z, pcv.y};
        const float py[4] = {pa.y, pb.x, pb.w, pcv.z};
        const float pz[4] = {pa.z, pb.y, pcv.x, pcv.w};
        const float vx[4] = {va.x, va.w, vb.z, vcv.y};
        const float vy[4] = {va.y, vb.x, vb.w, vcv.z};
        const float vz[4] = {va.z, vb.y, vcv.x, vcv.w};

        float nA[4], f[4], fp[4];
        #pragma unroll
        for (int r = 0; r < 4; ++r) {
            // local frame: Pl = (P - T) @ R, Vl = V @ R  (row-vector times R)
            const float qx = px[r] - t0, qy = py[r] - t1, qz = pz[r] - t2;
            const float plx = qx * r00 + qy * r10 + qz * r20;
            const float ply = qx * r01 + qy * r11 + qz * r21;
            const float plz = qx * r02 + qy * r12 + qz * r22;
            const float vlx = vx[r] * r00 + vy[r] * r10 + vz[r] * r20;
            const float vly = vx[r] * r01 + vy[r] * r11 + vz[r] * r21;
            const float vlz = vx[r] * r02 + vy[r] * r12 + vz[r] * r22;
            nA[r] = c * (vly * vly + vlz * vlz);                 // -A
            f[r]  = plx - c * (ply * ply + plz * plz);           // f(0)  = C
            fp[r] = vlx - 2.0f * c * (ply * vly + plz * vlz);    // f'(0) = B
        }

        // delta = f*f'/(f'^2 + damping), reciprocal via magic + 3 Newton steps
        // (den in [0.5, ~10]: normal range, bit-trick safe, always converges).
        // tmp   = f' - A*delta
        // f    <- f - delta*tmp          (= f - d*f' + A*d^2, exact quadratic)
        // f'   <- tmp - A*delta          (= f' - 2A*delta)
        #pragma unroll 1
        for (int it = 0; it < LM_ITERS; ++it) {
            #pragma unroll
            for (int r = 0; r < 4; ++r) {
                const float den = fmaf(fp[r], fp[r], DAMPING);
                float w = __uint_as_float(0x7EF127EAu - __float_as_uint(den));
                w = w * fmaf(-den, w, 2.0f);
                w = w * fmaf(-den, w, 2.0f);
                w = w * fmaf(-den, w, 2.0f);
                const float d   = (f[r] * fp[r]) * w;
                const float tmp = fmaf(nA[r], d, fp[r]);
                f[r]  = fmaf(-d, tmp, f[r]);
                fp[r] = fmaf(nA[r], d, tmp);
            }
        }

        #pragma unroll
        for (int r = 0; r < 4; ++r) {
            if (base + r < n)
                acc += (double)f[r] * (double)f[r];
        }
    }

    // wave(64) shuffle reduce -> LDS across 4 waves -> one f64 atomic per block
    for (int off = 32; off > 0; off >>= 1)
        acc += __shfl_down(acc, off, 64);
    __shared__ double sacc[4];
    const int lane = threadIdx.x & 63, wave = threadIdx.x >> 6;
    if (lane == 0) sacc[wave] = acc;
    __syncthreads();
    if (threadIdx.x == 0) {
        atomicAdd(ws, sacc[0] + sacc[1] + sacc[2] + sacc[3]);
    }
}

__global__ void rod_finalize(const double* __restrict__ ws,
                             const float* __restrict__ loss_in,
                             float* __restrict__ out, double inv_n)
{
    out[0] = (float)(ws[0] * inv_n + (double)loss_in[0]);
}

extern "C" void kernel_launch(void* const* d_in, const int* in_sizes, int n_in,
                              void* d_out, int out_size, void* d_ws, size_t ws_size,
                              hipStream_t stream) {
    const float* P       = (const float*)d_in[0];
    const float* V       = (const float*)d_in[1];
    const float* R       = (const float*)d_in[2];
    const float* T       = (const float*)d_in[3];
    const float* c       = (const float*)d_in[4];
    const float* loss_in = (const float*)d_in[5];

    const int n = in_sizes[0] / 3;           // number of rays

    // d_ws is poisoned to 0xAA before every launch — zero the accumulator.
    hipMemsetAsync(d_ws, 0, sizeof(double), stream);

    const int threads = (n + 3) / 4;         // 4 rays per thread
    const int block   = 256;
    const int grid    = (threads + block - 1) / block;
    rod_kernel<<<grid, block, 0, stream>>>(P, V, R, T, c, (double*)d_ws, n);
    rod_finalize<<<1, 1, 0, stream>>>((const double*)d_ws, loss_in,
                                      (float*)d_out, 1.0 / (double)n);
}

// Round 8
// 144.278 us; speedup vs baseline: 1.1521x; 1.1521x over previous
//
#include <hip/hip_runtime.h>

// NonImagingRod: per-ray damped-Newton (LM) root find on f(t) = A t^2 + B t + C.
// Round-8: R6's proven math + 2-chunk software pipeline per thread.
// R1/R6/R7 all pinned at ~66us with VALU issue only ~23-35us and memory at
// 24% of achievable: not issue-, not rcp-, not BW-bound. Diagnosis: identical
// waves launched together stay PHASE-LOCKED -> dependency stalls correlate ->
// SIMD idles even with several resident waves. Fix attempt: per-thread 2-chunk
// pipeline (prefetch chunk1 during chunk0 iterations) = independent VMEM+setup
// ILP inside each wave + natural wave desync + half the ramp overhead.
//
// Codegen notes (hard-won):
//  - 8 simultaneous iterated rays (R2-5): spill wall (VGPR capped 32-36,
//    FETCH +10-20MB noisy, VALUBusy 16%). 4 iterated rays + 24 prefetch regs
//    stays within the 64-VGPR tier (8 waves/SIMD preserved).
//  - No-spill signature: FETCH_SIZE stable ~49-50 MB. SGPR count is NOT a
//    spill signal (R6: SGPR 48, clean).
//  - Clamp(+-1000) provably inactive; rcp ~1ulp fine (absmax 0.0, R2-R7).

#define LM_ITERS 31
constexpr float DAMPING = 0.5f;

__global__ __launch_bounds__(256) void rod_kernel(
    const float* __restrict__ P, const float* __restrict__ V,
    const float* __restrict__ Rm, const float* __restrict__ Tv,
    const float* __restrict__ c_ptr, double* __restrict__ ws, int n)
{
    const float c  = c_ptr[0];
    const float r00 = Rm[0], r01 = Rm[1], r02 = Rm[2];
    const float r10 = Rm[3], r11 = Rm[4], r12 = Rm[5];
    const float r20 = Rm[6], r21 = Rm[7], r22 = Rm[8];
    const float t0 = Tv[0], t1 = Tv[1], t2 = Tv[2];

    const int tid      = blockIdx.x * blockDim.x + threadIdx.x;
    const int nthreads = gridDim.x * blockDim.x;
    const int g0 = tid;                 // chunk 0: rays [4*g0, 4*g0+4)
    const int g1 = tid + nthreads;      // chunk 1: rays [4*g1, 4*g1+4)

    const float4* P4 = (const float4*)P;
    const float4* V4 = (const float4*)V;

    double acc = 0.0;

    // ---- chunk 0 load ----
    float4 pa{}, pb{}, pcv{}, va{}, vb{}, vcv{};
    const bool has0 = (4 * g0 < n);
    if (has0) {
        pa = P4[g0 * 3 + 0]; pb = P4[g0 * 3 + 1]; pcv = P4[g0 * 3 + 2];
        va = V4[g0 * 3 + 0]; vb = V4[g0 * 3 + 1]; vcv = V4[g0 * 3 + 2];
    }

    // ---- setup helper (proven R6 form) ----
    float nA[4], f[4], fp[4];
    auto setup4 = [&](const float4& qa, const float4& qb, const float4& qc,
                      const float4& ua, const float4& ub, const float4& uc) {
        const float px[4] = {qa.x, qa.w, qb.z, qc.y};
        const float py[4] = {qa.y, qb.x, qb.w, qc.z};
        const float pz[4] = {qa.z, qb.y, qc.x, qc.w};
        const float wx[4] = {ua.x, ua.w, ub.z, uc.y};
        const float wy[4] = {ua.y, ub.x, ub.w, uc.z};
        const float wz[4] = {ua.z, ub.y, uc.x, uc.w};
        #pragma unroll
        for (int r = 0; r < 4; ++r) {
            const float qx = px[r] - t0, qy = py[r] - t1, qz = pz[r] - t2;
            const float plx = qx * r00 + qy * r10 + qz * r20;
            const float ply = qx * r01 + qy * r11 + qz * r21;
            const float plz = qx * r02 + qy * r12 + qz * r22;
            const float vlx = wx[r] * r00 + wy[r] * r10 + wz[r] * r20;
            const float vly = wx[r] * r01 + wy[r] * r11 + wz[r] * r21;
            const float vlz = wx[r] * r02 + wy[r] * r12 + wz[r] * r22;
            nA[r] = c * (vly * vly + vlz * vlz);                 // -A
            f[r]  = plx - c * (ply * ply + plz * plz);           // f(0)  = C
            fp[r] = vlx - 2.0f * c * (ply * vly + plz * vlz);    // f'(0) = B
        }
    };

    // delta = f*f'/(f'^2+damping); tmp = f' - A*delta;
    // f <- f - delta*tmp (exact quadratic); f' <- tmp - A*delta.
    auto iterate = [&]() {
        #pragma unroll 1
        for (int it = 0; it < LM_ITERS; ++it) {
            #pragma unroll
            for (int r = 0; r < 4; ++r) {
                const float den = fmaf(fp[r], fp[r], DAMPING);
                const float rcp = __builtin_amdgcn_rcpf(den);  // ~1 ulp; LM self-corrects
                const float d   = (f[r] * fp[r]) * rcp;
                const float tmp = fmaf(nA[r], d, fp[r]);
                f[r]  = fmaf(-d, tmp, f[r]);
                fp[r] = fmaf(nA[r], d, tmp);
            }
        }
    };

    setup4(pa, pb, pcv, va, vb, vcv);

    // ---- prefetch chunk 1 (independent: issues before/through chunk-0 loop) ----
    float4 qa1{}, qb1{}, qc1{}, ua1{}, ub1{}, uc1{};
    const bool has1 = (4 * g1 < n);
    if (has1) {
        qa1 = P4[g1 * 3 + 0]; qb1 = P4[g1 * 3 + 1]; qc1 = P4[g1 * 3 + 2];
        ua1 = V4[g1 * 3 + 0]; ub1 = V4[g1 * 3 + 1]; uc1 = V4[g1 * 3 + 2];
    }

    iterate();                           // chunk 0 (zeros if !has0: harmless)
    if (has0) {
        #pragma unroll
        for (int r = 0; r < 4; ++r)
            if (4 * g0 + r < n) acc += (double)f[r] * (double)f[r];
    }

    setup4(qa1, qb1, qc1, ua1, ub1, uc1);
    iterate();                           // chunk 1 (zeros if !has1: harmless)
    if (has1) {
        #pragma unroll
        for (int r = 0; r < 4; ++r)
            if (4 * g1 + r < n) acc += (double)f[r] * (double)f[r];
    }

    // wave(64) shuffle reduce -> LDS across 4 waves -> one f64 atomic per block
    for (int off = 32; off > 0; off >>= 1)
        acc += __shfl_down(acc, off, 64);
    __shared__ double sacc[4];
    const int lane = threadIdx.x & 63, wave = threadIdx.x >> 6;
    if (lane == 0) sacc[wave] = acc;
    __syncthreads();
    if (threadIdx.x == 0) {
        atomicAdd(ws, sacc[0] + sacc[1] + sacc[2] + sacc[3]);
    }
}

__global__ void rod_finalize(const double* __restrict__ ws,
                             const float* __restrict__ loss_in,
                             float* __restrict__ out, double inv_n)
{
    out[0] = (float)(ws[0] * inv_n + (double)loss_in[0]);
}

extern "C" void kernel_launch(void* const* d_in, const int* in_sizes, int n_in,
                              void* d_out, int out_size, void* d_ws, size_t ws_size,
                              hipStream_t stream) {
    const float* P       = (const float*)d_in[0];
    const float* V       = (const float*)d_in[1];
    const float* R       = (const float*)d_in[2];
    const float* T       = (const float*)d_in[3];
    const float* c       = (const float*)d_in[4];
    const float* loss_in = (const float*)d_in[5];

    const int n = in_sizes[0] / 3;           // number of rays

    // d_ws is poisoned to 0xAA before every launch — zero the accumulator.
    hipMemsetAsync(d_ws, 0, sizeof(double), stream);

    // 8 rays/thread as 2 pipelined 4-ray chunks.
    const int threads = (n + 7) / 8;
    const int block   = 256;
    const int grid    = (threads + block - 1) / block;
    rod_kernel<<<grid, block, 0, stream>>>(P, V, R, T, c, (double*)d_ws, n);
    rod_finalize<<<1, 1, 0, stream>>>((const double*)d_ws, loss_in,
                                      (float*)d_out, 1.0 / (double)n);
}

// Round 9
// 134.334 us; speedup vs baseline: 1.2374x; 1.0740x over previous
//
#include <hip/hip_runtime.h>

// NonImagingRod: per-ray damped-Newton (LM) root find on f(t) = A t^2 + B t + C.
// Round-9: R8's proven 2-chunk software pipeline deepened to 4 chunks/thread
// (straight-line, same code shape). R8 confirmed the phase-lock theory:
// cross-chunk independent work (prefetch + next setup) is what fills the SIMD
// (66 -> 43 us, VALUBusy 49%, no spill at VGPR 32). 4 chunks gives 3 of 4
// iterates overlap work (vs 1 of 2) and shrinks the grid to 1024 blocks =
// 4 blocks/CU = whole grid co-resident in ONE dispatch round (no 2nd ramp).
//
// Codegen notes (hard-won):
//  - 8 SIMULTANEOUSLY-iterated rays (R2-5): spill wall (VGPR capped 32-36,
//    FETCH noisy +10-20MB, VALUBusy 16%). 4 iterated rays + 24 prefetch regs
//    is the proven-clean shape (R8: VGPR 32, FETCH stable).
//  - No-spill signature: FETCH_SIZE stable ~49-50 MB (SGPR count is NOT one).
//  - Clamp(+-1000) provably inactive; rcp ~1ulp fine (absmax 0.0, R2-R8).

#define LM_ITERS 31
constexpr float DAMPING = 0.5f;

__global__ __launch_bounds__(256) void rod_kernel(
    const float* __restrict__ P, const float* __restrict__ V,
    const float* __restrict__ Rm, const float* __restrict__ Tv,
    const float* __restrict__ c_ptr, double* __restrict__ ws, int n)
{
    const float c  = c_ptr[0];
    const float r00 = Rm[0], r01 = Rm[1], r02 = Rm[2];
    const float r10 = Rm[3], r11 = Rm[4], r12 = Rm[5];
    const float r20 = Rm[6], r21 = Rm[7], r22 = Rm[8];
    const float t0 = Tv[0], t1 = Tv[1], t2 = Tv[2];

    const int tid      = blockIdx.x * blockDim.x + threadIdx.x;
    const int nthreads = gridDim.x * blockDim.x;

    const float4* P4 = (const float4*)P;
    const float4* V4 = (const float4*)V;

    double acc = 0.0;

    float nA[4], f[4], fp[4];
    auto setup4 = [&](const float4& qa, const float4& qb, const float4& qc,
                      const float4& ua, const float4& ub, const float4& uc) {
        const float px[4] = {qa.x, qa.w, qb.z, qc.y};
        const float py[4] = {qa.y, qb.x, qb.w, qc.z};
        const float pz[4] = {qa.z, qb.y, qc.x, qc.w};
        const float wx[4] = {ua.x, ua.w, ub.z, uc.y};
        const float wy[4] = {ua.y, ub.x, ub.w, uc.z};
        const float wz[4] = {ua.z, ub.y, uc.x, uc.w};
        #pragma unroll
        for (int r = 0; r < 4; ++r) {
            const float qx = px[r] - t0, qy = py[r] - t1, qz = pz[r] - t2;
            const float plx = qx * r00 + qy * r10 + qz * r20;
            const float ply = qx * r01 + qy * r11 + qz * r21;
            const float plz = qx * r02 + qy * r12 + qz * r22;
            const float vlx = wx[r] * r00 + wy[r] * r10 + wz[r] * r20;
            const float vly = wx[r] * r01 + wy[r] * r11 + wz[r] * r21;
            const float vlz = wx[r] * r02 + wy[r] * r12 + wz[r] * r22;
            nA[r] = c * (vly * vly + vlz * vlz);                 // -A
            f[r]  = plx - c * (ply * ply + plz * plz);           // f(0)  = C
            fp[r] = vlx - 2.0f * c * (ply * vly + plz * vlz);    // f'(0) = B
        }
    };

    // delta = f*f'/(f'^2+damping); tmp = f' - A*delta;
    // f <- f - delta*tmp (exact quadratic); f' <- tmp - A*delta.
    auto iterate = [&]() {
        #pragma unroll 1
        for (int it = 0; it < LM_ITERS; ++it) {
            #pragma unroll
            for (int r = 0; r < 4; ++r) {
                const float den = fmaf(fp[r], fp[r], DAMPING);
                const float rcp = __builtin_amdgcn_rcpf(den);  // ~1 ulp; LM self-corrects
                const float d   = (f[r] * fp[r]) * rcp;
                const float tmp = fmaf(nA[r], d, fp[r]);
                f[r]  = fmaf(-d, tmp, f[r]);
                fp[r] = fmaf(nA[r], d, tmp);
            }
        }
    };

    auto accum = [&](int g) {
        #pragma unroll
        for (int r = 0; r < 4; ++r)
            if (4 * g + r < n) acc += (double)f[r] * (double)f[r];
    };

    const int g0 = tid;
    const int g1 = tid + nthreads;
    const int g2 = tid + 2 * nthreads;
    const int g3 = tid + 3 * nthreads;

    // ---- chunk 0 load ----
    float4 a0{}, b0{}, c0{}, u0{}, v0{}, w0{};
    if (4 * g0 < n) {
        a0 = P4[g0 * 3 + 0]; b0 = P4[g0 * 3 + 1]; c0 = P4[g0 * 3 + 2];
        u0 = V4[g0 * 3 + 0]; v0 = V4[g0 * 3 + 1]; w0 = V4[g0 * 3 + 2];
    }
    setup4(a0, b0, c0, u0, v0, w0);

    // ---- prefetch chunk 1, iterate chunk 0 ----
    float4 a1{}, b1{}, c1{}, u1{}, v1{}, w1{};
    if (4 * g1 < n) {
        a1 = P4[g1 * 3 + 0]; b1 = P4[g1 * 3 + 1]; c1 = P4[g1 * 3 + 2];
        u1 = V4[g1 * 3 + 0]; v1 = V4[g1 * 3 + 1]; w1 = V4[g1 * 3 + 2];
    }
    iterate();
    accum(g0);

    // ---- prefetch chunk 2, iterate chunk 1 ----
    setup4(a1, b1, c1, u1, v1, w1);
    float4 a2{}, b2{}, c2{}, u2{}, v2{}, w2{};
    if (4 * g2 < n) {
        a2 = P4[g2 * 3 + 0]; b2 = P4[g2 * 3 + 1]; c2 = P4[g2 * 3 + 2];
        u2 = V4[g2 * 3 + 0]; v2 = V4[g2 * 3 + 1]; w2 = V4[g2 * 3 + 2];
    }
    iterate();
    accum(g1);

    // ---- prefetch chunk 3, iterate chunk 2 ----
    setup4(a2, b2, c2, u2, v2, w2);
    float4 a3{}, b3{}, c3{}, u3{}, v3{}, w3{};
    if (4 * g3 < n) {
        a3 = P4[g3 * 3 + 0]; b3 = P4[g3 * 3 + 1]; c3 = P4[g3 * 3 + 2];
        u3 = V4[g3 * 3 + 0]; v3 = V4[g3 * 3 + 1]; w3 = V4[g3 * 3 + 2];
    }
    iterate();
    accum(g2);

    // ---- iterate chunk 3 ----
    setup4(a3, b3, c3, u3, v3, w3);
    iterate();
    accum(g3);

    // wave(64) shuffle reduce -> LDS across 4 waves -> one f64 atomic per block
    for (int off = 32; off > 0; off >>= 1)
        acc += __shfl_down(acc, off, 64);
    __shared__ double sacc[4];
    const int lane = threadIdx.x & 63, wave = threadIdx.x >> 6;
    if (lane == 0) sacc[wave] = acc;
    __syncthreads();
    if (threadIdx.x == 0) {
        atomicAdd(ws, sacc[0] + sacc[1] + sacc[2] + sacc[3]);
    }
}

__global__ void rod_finalize(const double* __restrict__ ws,
                             const float* __restrict__ loss_in,
                             float* __restrict__ out, double inv_n)
{
    out[0] = (float)(ws[0] * inv_n + (double)loss_in[0]);
}

extern "C" void kernel_launch(void* const* d_in, const int* in_sizes, int n_in,
                              void* d_out, int out_size, void* d_ws, size_t ws_size,
                              hipStream_t stream) {
    const float* P       = (const float*)d_in[0];
    const float* V       = (const float*)d_in[1];
    const float* R       = (const float*)d_in[2];
    const float* T       = (const float*)d_in[3];
    const float* c       = (const float*)d_in[4];
    const float* loss_in = (const float*)d_in[5];

    const int n = in_sizes[0] / 3;           // number of rays

    // d_ws is poisoned to 0xAA before every launch — zero the accumulator.
    hipMemsetAsync(d_ws, 0, sizeof(double), stream);

    // 16 rays/thread as 4 pipelined 4-ray chunks -> 1024 blocks = one
    // fully-co-resident dispatch round (4 blocks/CU).
    const int threads = (n + 15) / 16;
    const int block   = 256;
    const int grid    = (threads + block - 1) / block;
    rod_kernel<<<grid, block, 0, stream>>>(P, V, R, T, c, (double*)d_ws, n);
    rod_finalize<<<1, 1, 0, stream>>>((const double*)d_ws, loss_in,
                                      (float*)d_out, 1.0 / (double)n);
}